// Round 11
// baseline (1254.925 us; speedup 1.0000x reference)
//
#include <hip/hip_runtime.h>
#include <hip/hip_bf16.h>

typedef short bf16x8 __attribute__((ext_vector_type(8)));
typedef float f32x4  __attribute__((ext_vector_type(4)));

#define TSTEPS 1000
#define BATCH  256
#define NIN    256
#define HID    128
#define TC     25
#define LOG2E  1.44269504088896f

// SoA xp: xp4 = uint4 {r01,r23,z01,z23}, xp2 = uint2 {n01,n23}; ALL preacts
// prescaled by log2e; r,z have bih+bhh folded, n has bih folded (bhh_n is
// added in gru_rec's gate code). index = (dir*TSTEPS+t)*8192 + gidx,
// gidx = (btile*8+wave)*64+lane.
#define GIDX_N 8192
#define XP4_ELEMS (2ull*TSTEPS*GIDX_N)
#define XP2_OFF_BYTES (XP4_ELEMS*16ull)           // 262,144,000
#define XP_NEED (XP4_ELEMS*16ull + 2ull*TSTEPS*GIDX_N*8ull)   // 393,216,000

__device__ __forceinline__ ushort f2bf(float f){
  union { float f; unsigned u; } v; v.f = f;
  unsigned r = v.u + 0x7fffu + ((v.u >> 16) & 1u);
  return (ushort)(r >> 16);
}
__device__ __forceinline__ uint pk2(float lo, float hi){
  __hip_bfloat162 h = __float22bfloat162_rn(make_float2(lo, hi));
  union { __hip_bfloat162 h; uint u; } c; c.h = h; return c.u;
}
__device__ __forceinline__ float bflo(uint w){ union{uint u;float f;}c; c.u = w<<16; return c.f; }
__device__ __forceinline__ float bfhi(uint w){ union{uint u;float f;}c; c.u = w & 0xffff0000u; return c.f; }

__device__ __forceinline__ float sigmoid_fast(float x){
  return __builtin_amdgcn_rcpf(1.f + __expf(-x));
}
__device__ __forceinline__ float tanh_fast(float a){
  const float e = __expf(2.f*fabsf(a));
  const float t = fmaf(-2.f, __builtin_amdgcn_rcpf(e + 1.f), 1.f);
  return copysignf(t, a);
}
__device__ __forceinline__ bf16x8 ld_w8(const float* p){
  union { uint u[4]; bf16x8 v; } c;
  c.u[0]=pk2(p[0],p[1]); c.u[1]=pk2(p[2],p[3]);
  c.u[2]=pk2(p[4],p[5]); c.u[3]=pk2(p[6],p[7]);
  return c.v;
}
__device__ __forceinline__ bf16x8 ld_w8s(const float* p, float s){
  union { uint u[4]; bf16x8 v; } c;
  c.u[0]=pk2(p[0]*s,p[1]*s); c.u[1]=pk2(p[2]*s,p[3]*s);
  c.u[2]=pk2(p[4]*s,p[5]*s); c.u[3]=pk2(p[6]*s,p[7]*s);
  return c.v;
}

// ============================================================================
// Input-projection GEMM — barrier-free direct-load version.
// No LDS, no __syncthreads after weight preload: each wave loads its own
// x fragments fp32->bf16 in registers (8x redundant convert, L1-cached
// loads), depth-1 register prefetch. Time dim is fully parallel, so waves
// drift freely and hide each other's memory latency. Arithmetic identical
// to the staged version (same pk2 + prescaled-weight MFMA + bias C-init).
// ============================================================================
__global__ __launch_bounds__(512) void xp_gemm(
    const float* __restrict__ y_aux,
    const float* __restrict__ Wf, const float* __restrict__ bihf, const float* __restrict__ bhhf,
    const float* __restrict__ Wb, const float* __restrict__ bihb, const float* __restrict__ bhhb,
    uint4* __restrict__ xp4, uint2* __restrict__ xp2)
{
  const int nch = TSTEPS/TC;               // 40
  const int blk = blockIdx.x;
  const int dir = blk / (16*nch);
  const int rem = blk % (16*nch);
  const int btile = rem / nch;
  const int tch = rem % nch;
  const int b0 = btile*16;
  const int tid=threadIdx.x, wave=tid>>6, lane=tid&63, lrow=lane&15, lgrp=lane>>4;
  const float* Wih = dir? Wb : Wf;
  const float* bih = dir? bihb : bihf;
  const float* bhh = dir? bhhb : bhhf;

  bf16x8 wf[3][8];
  f32x4 cinit[3];
  #pragma unroll
  for (int t3=0;t3<3;++t3){
    const int g = t3*128 + wave*16 + lrow;
    #pragma unroll
    for (int kk=0;kk<8;++kk)
      wf[t3][kk] = ld_w8s(Wih + g*NIN + kk*32 + lgrp*8, LOG2E);
    const float bv = LOG2E * (bih[g] + (t3<2 ? bhh[g] : 0.f));
    cinit[t3][0]=bv; cinit[t3][1]=bv; cinit[t3][2]=bv; cinit[t3][3]=bv;
  }

  // per-lane x fragment base: row (b0+lrow), chunk start, col offset lgrp*8
  const float* xbase = y_aux + (size_t)(b0+lrow)*(TSTEPS*NIN)
                     + (size_t)(tch*TC)*NIN + lgrp*8;
  size_t sidx = ((size_t)dir*TSTEPS + (size_t)(tch*TC))*GIDX_N
              + (size_t)((btile*8 + wave)*64 + lane);

  // prefetch t=0 fragments (8 kslices x 32B)
  float4 pa[8], pb[8];
  #pragma unroll
  for (int kk=0;kk<8;++kk){
    const float* p = xbase + kk*32;
    pa[kk] = *(const float4*)p;
    pb[kk] = *(const float4*)(p+4);
  }

  for (int k=0;k<TC;++k){
    // convert current step's fragments
    bf16x8 a[8];
    #pragma unroll
    for (int kk=0;kk<8;++kk){
      union{uint u[4]; bf16x8 v;} c;
      c.u[0]=pk2(pa[kk].x,pa[kk].y); c.u[1]=pk2(pa[kk].z,pa[kk].w);
      c.u[2]=pk2(pb[kk].x,pb[kk].y); c.u[3]=pk2(pb[kk].z,pb[kk].w);
      a[kk] = c.v;
    }
    // prefetch next step (clamped; uniform branch-free)
    const int tn = (k+1 < TC) ? (k+1) : (TC-1);
    const float* pn = xbase + (size_t)tn*NIN;
    #pragma unroll
    for (int kk=0;kk<8;++kk){
      pa[kk] = *(const float4*)(pn + kk*32);
      pb[kk] = *(const float4*)(pn + kk*32 + 4);
    }
    // MFMA (bias folded into C-init, loop-invariant)
    f32x4 a0=cinit[0], a1=cinit[1], a2=cinit[2];
    #pragma unroll
    for (int kk=0;kk<8;++kk){
      a0 = __builtin_amdgcn_mfma_f32_16x16x32_bf16(a[kk], wf[0][kk], a0, 0,0,0);
      a1 = __builtin_amdgcn_mfma_f32_16x16x32_bf16(a[kk], wf[1][kk], a1, 0,0,0);
      a2 = __builtin_amdgcn_mfma_f32_16x16x32_bf16(a[kk], wf[2][kk], a2, 0,0,0);
    }
    uint4 o4; o4.x=pk2(a0[0],a0[1]); o4.y=pk2(a0[2],a0[3]);
              o4.z=pk2(a1[0],a1[1]); o4.w=pk2(a1[2],a1[3]);
    uint2 o2; o2.x=pk2(a2[0],a2[1]); o2.y=pk2(a2[2],a2[3]);
    xp4[sidx]=o4; xp2[sidx]=o2; sidx += GIDX_N;
  }
}

// ============================================================================
// Serial recurrence — R3 VERBATIM (measured 697us). 32 blocks (dir x btile),
// 8 waves; wave w owns gate tiles {w, 8+w, 16+w} = (r,z,n) for h columns
// [16w,16w+16). Zero-init accumulators, xp added post-MFMA, depth-2 prefetch.
// ============================================================================
__global__ __launch_bounds__(512) void gru_rec(
    const uint4* __restrict__ xp4, const uint2* __restrict__ xp2,
    const float* __restrict__ Whhf, const float* __restrict__ bhhf,
    const float* __restrict__ Whhb, const float* __restrict__ bhhb,
    float* __restrict__ out)
{
  const int blk=blockIdx.x, dir=blk>>4, btile=blk&15, b0=btile<<4;
  const int tid=threadIdx.x, wave=tid>>6, lane=tid&63, lrow=lane&15, lgrp=lane>>4;
  const float* Whh = dir? Whhb : Whhf;
  const float* bhh = dir? bhhb : bhhf;

  __shared__ __align__(16) ushort hbuf[2][16][136];

  bf16x8 whh[3][4];
  #pragma unroll
  for (int t3=0;t3<3;++t3){
    const int g = t3*128 + wave*16 + lrow;
    #pragma unroll
    for (int kk=0;kk<4;++kk)
      whh[t3][kk] = ld_w8s(Whh + g*HID + kk*32 + lgrp*8, LOG2E);
  }
  const int hcol = wave*16 + lrow;
  const float bh2s = LOG2E * bhh[256 + hcol];

  { ushort* hb=&hbuf[0][0][0]; for (int i=tid;i<16*136;i+=512) hb[i]=0; }

  const int tt0 = dir? (TSTEPS-1):0;
  const long long d4 = dir? -(long long)GIDX_N : (long long)GIDX_N;
  const size_t gbase = ((size_t)dir*TSTEPS + (size_t)tt0)*GIDX_N
                     + (size_t)((btile*8+wave)*64+lane);
  const uint4* q4p = xp4 + gbase;
  const uint2* q2p = xp2 + gbase;
  uint4 q40 = q4p[0], q41 = q4p[d4];
  uint2 q20 = q2p[0], q21 = q2p[d4];
  const uint4* f4 = q4p + 2*d4;
  const uint2* f2 = q2p + 2*d4;

  float* op = out + 8192 + (size_t)tt0*(BATCH*2*HID)
            + (size_t)(b0 + lgrp*4)*(2*HID) + dir*HID + hcol;
  const long long odel = dir? -(long long)(BATCH*2*HID) : (long long)(BATCH*2*HID);

  float hm[4]={0,0,0,0};
  __syncthreads();

  for (int s=0;s<TSTEPS;++s){
    const int cur=s&1, nxt=cur^1;
    // depth-2 prefetch (wrap-safe inside xp4/xp2 allocations)
    uint4 q42 = *f4; f4 += d4;
    uint2 q22 = *f2; f2 += d4;

    f32x4 ar={0,0,0,0}, az={0,0,0,0}, an={0,0,0,0};
    #pragma unroll
    for (int kk=0;kk<4;++kk){
      bf16x8 a = *(const bf16x8*)&hbuf[cur][lrow][kk*32 + lgrp*8];
      ar = __builtin_amdgcn_mfma_f32_16x16x32_bf16(a, whh[0][kk], ar, 0,0,0);
      az = __builtin_amdgcn_mfma_f32_16x16x32_bf16(a, whh[1][kk], az, 0,0,0);
      an = __builtin_amdgcn_mfma_f32_16x16x32_bf16(a, whh[2][kk], an, 0,0,0);
    }

    float hv[4];
    {
      const float xr[4] = {bflo(q40.x),bfhi(q40.x),bflo(q40.y),bfhi(q40.y)};
      const float xz[4] = {bflo(q40.z),bfhi(q40.z),bflo(q40.w),bfhi(q40.w)};
      const float xn[4] = {bflo(q20.x),bfhi(q20.x),bflo(q20.y),bfhi(q20.y)};
      #pragma unroll
      for (int i=0;i<4;++i){
        const float r = __builtin_amdgcn_rcpf(1.f + __builtin_amdgcn_exp2f(-(ar[i]+xr[i])));
        const float z = __builtin_amdgcn_rcpf(1.f + __builtin_amdgcn_exp2f(-(az[i]+xz[i])));
        const float y  = fmaf(r, an[i]+bh2s, xn[i]);
        const float y2 = y + y;
        const float e  = __builtin_amdgcn_exp2f(fabsf(y2));
        const float t  = fmaf(-2.f, __builtin_amdgcn_rcpf(e+1.f), 1.f);
        const float n  = copysignf(t, y);
        hv[i] = fmaf(z, hm[i]-n, n);
        hm[i] = hv[i];
      }
    }
    const uint p01 = pk2(hv[0],hv[1]);
    const uint p23 = pk2(hv[2],hv[3]);
    hbuf[nxt][lgrp*4+0][hcol] = (ushort)p01;
    hbuf[nxt][lgrp*4+1][hcol] = (ushort)(p01>>16);
    hbuf[nxt][lgrp*4+2][hcol] = (ushort)p23;
    hbuf[nxt][lgrp*4+3][hcol] = (ushort)(p23>>16);
    op[0]   = hv[0];
    op[256] = hv[1];
    op[512] = hv[2];
    op[768] = hv[3];
    op += odel;
    q40=q41; q41=q42; q20=q21; q21=q22;
    asm volatile("s_waitcnt lgkmcnt(0)\n\ts_barrier" ::: "memory");
  }
}

// ============================================================================
// Fallback fused kernel (used only if ws_size is too small)
// ============================================================================
__global__ __launch_bounds__(512) void gru_fused(
    const float* __restrict__ y_aux,
    const float* __restrict__ W_ih_f, const float* __restrict__ W_hh_f,
    const float* __restrict__ b_ih_f, const float* __restrict__ b_hh_f,
    const float* __restrict__ W_ih_b, const float* __restrict__ W_hh_b,
    const float* __restrict__ b_ih_b, const float* __restrict__ b_hh_b,
    float* __restrict__ out)
{
  const int blk  = blockIdx.x;
  const int dir  = blk >> 4;
  const int b0   = (blk & 15) << 4;
  const int tid  = threadIdx.x;
  const int wave = tid >> 6;
  const int lane = tid & 63;
  const int lrow = lane & 15;
  const int lgrp = lane >> 4;

  const float* Wih = dir ? W_ih_b : W_ih_f;
  const float* Whh = dir ? W_hh_b : W_hh_f;
  const float* bih = dir ? b_ih_b : b_ih_f;
  const float* bhh = dir ? b_hh_b : b_hh_f;

  __shared__ __align__(16) ushort hbuf[2][16][136];
  __shared__ __align__(16) ushort xbuf[2][16][264];

  bf16x8 wih_f[3][8];
  bf16x8 whh_f[3][4];
  #pragma unroll
  for (int t3 = 0; t3 < 3; ++t3){
    const int g = t3*128 + wave*16 + lrow;
    #pragma unroll
    for (int kk = 0; kk < 8; ++kk) wih_f[t3][kk] = ld_w8(Wih + g*NIN + kk*32 + lgrp*8);
    #pragma unroll
    for (int kk = 0; kk < 4; ++kk) whh_f[t3][kk] = ld_w8(Whh + g*HID + kk*32 + lgrp*8);
  }
  float bihv[3], bhhv[3];
  #pragma unroll
  for (int t3 = 0; t3 < 3; ++t3){
    const int g = t3*128 + wave*16 + lrow;
    bihv[t3] = bih[g];
    bhhv[t3] = bhh[g];
  }

  for (int i = tid; i < 2*16*136; i += 512) ((ushort*)hbuf)[i] = 0;
  {
    const int row = tid >> 5, f8 = tid & 31;
    const int t0  = dir ? (TSTEPS-1) : 0;
    const float* p = y_aux + (size_t)(b0+row)*(TSTEPS*NIN) + (size_t)t0*NIN + f8*8;
    union{uint u[4]; bf16x8 v;} c;
    float4 a = *(const float4*)p; float4 b = *(const float4*)(p+4);
    c.u[0]=pk2(a.x,a.y); c.u[1]=pk2(a.z,a.w); c.u[2]=pk2(b.x,b.y); c.u[3]=pk2(b.z,b.w);
    *(bf16x8*)&xbuf[0][row][f8*8] = c.v;
  }
  __syncthreads();

  float hm[4] = {0.f, 0.f, 0.f, 0.f};
  const int hcol = wave*16 + lrow;
  float* outr = out + 8192;

  for (int s = 0; s < TSTEPS; ++s){
    const int tt  = dir ? (TSTEPS-1-s) : s;
    const int cur = s & 1, nxt = cur ^ 1;
    const int tn   = dir ? (tt-1) : (tt+1);
    const int prow = tid >> 5, pf8 = tid & 31;
    const bool more = (s < TSTEPS-1);
    float4 pa, pb;
    if (more){
      const float* p = y_aux + (size_t)(b0+prow)*(TSTEPS*NIN) + (size_t)tn*NIN + pf8*8;
      pa = *(const float4*)p;
      pb = *(const float4*)(p+4);
    }

    f32x4 a_rh = {0,0,0,0}, a_zh = {0,0,0,0}, a_nh = {0,0,0,0};
    f32x4 a_rx = {0,0,0,0}, a_zx = {0,0,0,0}, a_nx = {0,0,0,0};
    #pragma unroll
    for (int kk = 0; kk < 4; ++kk){
      bf16x8 a = *(const bf16x8*)&hbuf[cur][lrow][kk*32 + lgrp*8];
      a_rh = __builtin_amdgcn_mfma_f32_16x16x32_bf16(a, whh_f[0][kk], a_rh, 0,0,0);
      a_zh = __builtin_amdgcn_mfma_f32_16x16x32_bf16(a, whh_f[1][kk], a_zh, 0,0,0);
      a_nh = __builtin_amdgcn_mfma_f32_16x16x32_bf16(a, whh_f[2][kk], a_nh, 0,0,0);
    }
    #pragma unroll
    for (int kk = 0; kk < 8; ++kk){
      bf16x8 a = *(const bf16x8*)&xbuf[cur][lrow][kk*32 + lgrp*8];
      a_rx = __builtin_amdgcn_mfma_f32_16x16x32_bf16(a, wih_f[0][kk], a_rx, 0,0,0);
      a_zx = __builtin_amdgcn_mfma_f32_16x16x32_bf16(a, wih_f[1][kk], a_zx, 0,0,0);
      a_nx = __builtin_amdgcn_mfma_f32_16x16x32_bf16(a, wih_f[2][kk], a_nx, 0,0,0);
    }

    #pragma unroll
    for (int i = 0; i < 4; ++i){
      const float rp  = a_rh[i] + a_rx[i] + bihv[0] + bhhv[0];
      const float zp  = a_zh[i] + a_zx[i] + bihv[1] + bhhv[1];
      const float hnp = a_nh[i] + bhhv[2];
      const float xnp = a_nx[i] + bihv[2];
      const float r = sigmoid_fast(rp);
      const float z = sigmoid_fast(zp);
      const float n = tanh_fast(fmaf(r, hnp, xnp));
      const float hv = n + z*(hm[i] - n);
      hm[i] = hv;
      outr[(size_t)tt*(BATCH*2*HID) + (size_t)(b0 + lgrp*4 + i)*(2*HID)
           + dir*HID + hcol] = hv;
      hbuf[nxt][lgrp*4 + i][hcol] = f2bf(hv);
    }

    if (more){
      union{uint u[4]; bf16x8 v;} c;
      c.u[0]=pk2(pa.x,pa.y); c.u[1]=pk2(pa.z,pa.w); c.u[2]=pk2(pb.x,pb.y); c.u[3]=pk2(pb.z,pb.w);
      *(bf16x8*)&xbuf[nxt][prow][pf8*8] = c.v;
    }
    __syncthreads();
  }
}

// mu_0 / log_var_0 heads: temp = [zeros(B,L), hn0], so only W[:, L:] matters.
__global__ void heads(const float* __restrict__ out_rnn,
    const float* __restrict__ W_mu, const float* __restrict__ b_mu,
    const float* __restrict__ W_lv, const float* __restrict__ b_lv,
    float* __restrict__ out)
{
  const int oid   = blockIdx.x*256 + threadIdx.x;
  const int which = oid >> 12;
  const int r     = oid & 4095;
  const int b = r >> 4, j = r & 15;
  const float* W    = which ? W_lv : W_mu;
  const float* bias = which ? b_lv : b_mu;
  const float* h = out_rnn + b*256;
  const float* w = W + j*272 + 16;
  float acc = bias[j];
  for (int c = 0; c < 256; c += 4){
    acc += h[c]*w[c] + h[c+1]*w[c+1] + h[c+2]*w[c+2] + h[c+3]*w[c+3];
  }
  out[(which << 12) + r] = acc;
}

extern "C" void kernel_launch(void* const* d_in, const int* in_sizes, int n_in,
                              void* d_out, int out_size, void* d_ws, size_t ws_size,
                              hipStream_t stream)
{
  const float* y    = (const float*)d_in[0];
  const float* Wihf = (const float*)d_in[1];
  const float* Whhf = (const float*)d_in[2];
  const float* bihf = (const float*)d_in[3];
  const float* bhhf = (const float*)d_in[4];
  const float* Wihb = (const float*)d_in[5];
  const float* Whhb = (const float*)d_in[6];
  const float* bihb = (const float*)d_in[7];
  const float* bhhb = (const float*)d_in[8];
  const float* Wmu  = (const float*)d_in[9];
  const float* bmu  = (const float*)d_in[10];
  const float* Wlv  = (const float*)d_in[11];
  const float* blv  = (const float*)d_in[12];
  float* out = (float*)d_out;

  if (ws_size >= (size_t)XP_NEED){
    uint4* xp4 = (uint4*)d_ws;
    uint2* xp2 = (uint2*)((char*)d_ws + XP2_OFF_BYTES);
    xp_gemm<<<dim3(2*16*(TSTEPS/TC)), dim3(512), 0, stream>>>(
        y, Wihf, bihf, bhhf, Wihb, bihb, bhhb, xp4, xp2);
    gru_rec<<<dim3(32), dim3(512), 0, stream>>>(
        xp4, xp2, Whhf, bhhf, Whhb, bhhb, out);
  } else {
    gru_fused<<<dim3(32), dim3(512), 0, stream>>>(
        y, Wihf, Whhf, bihf, bhhf, Wihb, Whhb, bihb, bhhb, out);
  }
  heads<<<dim3(32), dim3(256), 0, stream>>>(out + 8192, Wmu, bmu, Wlv, blv, out);
}

// Round 13
// 935.583 us; speedup vs baseline: 1.3413x; 1.3413x over previous
//
#include <hip/hip_runtime.h>
#include <hip/hip_bf16.h>

typedef short bf16x8 __attribute__((ext_vector_type(8)));
typedef float f32x4  __attribute__((ext_vector_type(4)));

#define TSTEPS 1000
#define BATCH  256
#define NIN    256
#define HID    128
#define TC     20                      // MUST be even (pair-unrolled loop)
#define LOG2E  1.44269504088896f

// SoA xp: xp4 = uint4 {r01,r23,z01,z23}, xp2 = uint2 {n01,n23}; ALL preacts
// prescaled by log2e; r,z have bih+bhh folded, n has bih folded (bhh_n is
// added in gru_rec's gate code). index = (dir*TSTEPS+t)*8192 + gidx,
// gidx = (btile*8+wave)*64+lane.
#define GIDX_N 8192
#define XP4_ELEMS (2ull*TSTEPS*GIDX_N)
#define XP2_OFF_BYTES (XP4_ELEMS*16ull)           // 262,144,000
#define XP_NEED (XP4_ELEMS*16ull + 2ull*TSTEPS*GIDX_N*8ull)   // 393,216,000

__device__ __forceinline__ ushort f2bf(float f){
  union { float f; unsigned u; } v; v.f = f;
  unsigned r = v.u + 0x7fffu + ((v.u >> 16) & 1u);
  return (ushort)(r >> 16);
}
__device__ __forceinline__ uint pk2(float lo, float hi){
  __hip_bfloat162 h = __float22bfloat162_rn(make_float2(lo, hi));
  union { __hip_bfloat162 h; uint u; } c; c.h = h; return c.u;
}
__device__ __forceinline__ float bflo(uint w){ union{uint u;float f;}c; c.u = w<<16; return c.f; }
__device__ __forceinline__ float bfhi(uint w){ union{uint u;float f;}c; c.u = w & 0xffff0000u; return c.f; }

__device__ __forceinline__ float sigmoid_fast(float x){
  return __builtin_amdgcn_rcpf(1.f + __expf(-x));
}
__device__ __forceinline__ float tanh_fast(float a){
  const float e = __expf(2.f*fabsf(a));
  const float t = fmaf(-2.f, __builtin_amdgcn_rcpf(e + 1.f), 1.f);
  return copysignf(t, a);
}
__device__ __forceinline__ bf16x8 ld_w8(const float* p){
  union { uint u[4]; bf16x8 v; } c;
  c.u[0]=pk2(p[0],p[1]); c.u[1]=pk2(p[2],p[3]);
  c.u[2]=pk2(p[4],p[5]); c.u[3]=pk2(p[6],p[7]);
  return c.v;
}
__device__ __forceinline__ bf16x8 ld_w8s(const float* p, float s){
  union { uint u[4]; bf16x8 v; } c;
  c.u[0]=pk2(p[0]*s,p[1]*s); c.u[1]=pk2(p[2]*s,p[3]*s);
  c.u[2]=pk2(p[4]*s,p[5]*s); c.u[3]=pk2(p[6]*s,p[7]*s);
  return c.v;
}

// ============================================================================
// Input-projection GEMM (R10/R6 staged version; TC=20 -> 1600 blocks, 6.25
// rounds @ ~89% tail efficiency; TC even as the loop is pair-unrolled).
// Weights prescaled by log2e; biases folded via loop-invariant MFMA C-init;
// depth-2 register prefetch, clamped.
// ============================================================================
__global__ __launch_bounds__(512) void xp_gemm(
    const float* __restrict__ y_aux,
    const float* __restrict__ Wf, const float* __restrict__ bihf, const float* __restrict__ bhhf,
    const float* __restrict__ Wb, const float* __restrict__ bihb, const float* __restrict__ bhhb,
    uint4* __restrict__ xp4, uint2* __restrict__ xp2)
{
  const int nch = TSTEPS/TC;               // 50
  const int blk = blockIdx.x;
  const int dir = blk / (16*nch);
  const int rem = blk % (16*nch);
  const int btile = rem / nch;
  const int tch = rem % nch;
  const int b0 = btile*16;
  const int tid=threadIdx.x, wave=tid>>6, lane=tid&63, lrow=lane&15, lgrp=lane>>4;
  const float* Wih = dir? Wb : Wf;
  const float* bih = dir? bihb : bihf;
  const float* bhh = dir? bhhb : bhhf;

  __shared__ __align__(16) ushort xsh[2][16][264];

  bf16x8 wf[3][8];
  f32x4 cinit[3];
  #pragma unroll
  for (int t3=0;t3<3;++t3){
    const int g = t3*128 + wave*16 + lrow;
    #pragma unroll
    for (int kk=0;kk<8;++kk)
      wf[t3][kk] = ld_w8s(Wih + g*NIN + kk*32 + lgrp*8, LOG2E);
    const float bv = LOG2E * (bih[g] + (t3<2 ? bhh[g] : 0.f));
    cinit[t3][0]=bv; cinit[t3][1]=bv; cinit[t3][2]=bv; cinit[t3][3]=bv;
  }

  const int row = tid>>5, f8 = tid&31;
  const float* xsrc = y_aux + (size_t)(b0+row)*(TSTEPS*NIN) + (size_t)(tch*TC)*NIN + f8*8;
  {
    float4 a = *(const float4*)xsrc;
    float4 b = *(const float4*)(xsrc+4);
    union{uint u[4]; bf16x8 v;} c;
    c.u[0]=pk2(a.x,a.y); c.u[1]=pk2(a.z,a.w); c.u[2]=pk2(b.x,b.y); c.u[3]=pk2(b.z,b.w);
    *(bf16x8*)&xsh[0][row][f8*8] = c.v;
  }
  // depth-2 prefetch: t=1 and t=2 (TC >= 3)
  float4 Aa = *(const float4*)(xsrc + 1*NIN), Ab = *(const float4*)(xsrc + 1*NIN + 4);
  float4 Ba = *(const float4*)(xsrc + 2*NIN), Bb = *(const float4*)(xsrc + 2*NIN + 4);
  __syncthreads();

  size_t sidx = ((size_t)dir*TSTEPS + (size_t)(tch*TC))*GIDX_N
              + (size_t)((btile*8 + wave)*64 + lane);

  for (int k=0;k<TC;k+=2){
    // ----- step k (reads xsh[0], writes Aa/Ab -> xsh[1]) -----
    {
      f32x4 a0=cinit[0], a1=cinit[1], a2=cinit[2];
      #pragma unroll
      for (int kk=0;kk<8;++kk){
        bf16x8 a = *(const bf16x8*)&xsh[0][lrow][kk*32 + lgrp*8];
        a0 = __builtin_amdgcn_mfma_f32_16x16x32_bf16(a, wf[0][kk], a0, 0,0,0);
        a1 = __builtin_amdgcn_mfma_f32_16x16x32_bf16(a, wf[1][kk], a1, 0,0,0);
        a2 = __builtin_amdgcn_mfma_f32_16x16x32_bf16(a, wf[2][kk], a2, 0,0,0);
      }
      uint4 o4; o4.x=pk2(a0[0],a0[1]); o4.y=pk2(a0[2],a0[3]);
                o4.z=pk2(a1[0],a1[1]); o4.w=pk2(a1[2],a1[3]);
      uint2 o2; o2.x=pk2(a2[0],a2[1]); o2.y=pk2(a2[2],a2[3]);
      xp4[sidx]=o4; xp2[sidx]=o2; sidx += GIDX_N;
      union{uint u[4]; bf16x8 v;} c;
      c.u[0]=pk2(Aa.x,Aa.y); c.u[1]=pk2(Aa.z,Aa.w); c.u[2]=pk2(Ab.x,Ab.y); c.u[3]=pk2(Ab.z,Ab.w);
      *(bf16x8*)&xsh[1][row][f8*8] = c.v;
      const int t3 = (k+3 <= TC-1) ? (k+3) : (TC-1);     // uniform, clamped
      Aa = *(const float4*)(xsrc + (size_t)t3*NIN);
      Ab = *(const float4*)(xsrc + (size_t)t3*NIN + 4);
      asm volatile("s_waitcnt lgkmcnt(0)\n\ts_barrier" ::: "memory");
    }
    // ----- step k+1 (reads xsh[1], writes Ba/Bb -> xsh[0]) -----
    {
      f32x4 a0=cinit[0], a1=cinit[1], a2=cinit[2];
      #pragma unroll
      for (int kk=0;kk<8;++kk){
        bf16x8 a = *(const bf16x8*)&xsh[1][lrow][kk*32 + lgrp*8];
        a0 = __builtin_amdgcn_mfma_f32_16x16x32_bf16(a, wf[0][kk], a0, 0,0,0);
        a1 = __builtin_amdgcn_mfma_f32_16x16x32_bf16(a, wf[1][kk], a1, 0,0,0);
        a2 = __builtin_amdgcn_mfma_f32_16x16x32_bf16(a, wf[2][kk], a2, 0,0,0);
      }
      uint4 o4; o4.x=pk2(a0[0],a0[1]); o4.y=pk2(a0[2],a0[3]);
                o4.z=pk2(a1[0],a1[1]); o4.w=pk2(a1[2],a1[3]);
      uint2 o2; o2.x=pk2(a2[0],a2[1]); o2.y=pk2(a2[2],a2[3]);
      xp4[sidx]=o4; xp2[sidx]=o2; sidx += GIDX_N;
      union{uint u[4]; bf16x8 v;} c;
      c.u[0]=pk2(Ba.x,Ba.y); c.u[1]=pk2(Ba.z,Ba.w); c.u[2]=pk2(Bb.x,Bb.y); c.u[3]=pk2(Bb.z,Bb.w);
      *(bf16x8*)&xsh[0][row][f8*8] = c.v;
      const int t4 = (k+4 <= TC-1) ? (k+4) : (TC-1);
      Ba = *(const float4*)(xsrc + (size_t)t4*NIN);
      Bb = *(const float4*)(xsrc + (size_t)t4*NIN + 4);
      asm volatile("s_waitcnt lgkmcnt(0)\n\ts_barrier" ::: "memory");
    }
  }
}

// ============================================================================
// Serial recurrence — R3 VERBATIM (measured 690-700us across 3 benches).
// 32 blocks (dir x btile), 8 waves; wave w owns gate tiles {w, 8+w, 16+w}
// = (r,z,n) for h columns [16w,16w+16). Zero-init accumulators, xp added
// post-MFMA, depth-2 prefetch.
// ============================================================================
__global__ __launch_bounds__(512) void gru_rec(
    const uint4* __restrict__ xp4, const uint2* __restrict__ xp2,
    const float* __restrict__ Whhf, const float* __restrict__ bhhf,
    const float* __restrict__ Whhb, const float* __restrict__ bhhb,
    float* __restrict__ out)
{
  const int blk=blockIdx.x, dir=blk>>4, btile=blk&15, b0=btile<<4;
  const int tid=threadIdx.x, wave=tid>>6, lane=tid&63, lrow=lane&15, lgrp=lane>>4;
  const float* Whh = dir? Whhb : Whhf;
  const float* bhh = dir? bhhb : bhhf;

  __shared__ __align__(16) ushort hbuf[2][16][136];

  bf16x8 whh[3][4];
  #pragma unroll
  for (int t3=0;t3<3;++t3){
    const int g = t3*128 + wave*16 + lrow;
    #pragma unroll
    for (int kk=0;kk<4;++kk)
      whh[t3][kk] = ld_w8s(Whh + g*HID + kk*32 + lgrp*8, LOG2E);
  }
  const int hcol = wave*16 + lrow;
  const float bh2s = LOG2E * bhh[256 + hcol];

  { ushort* hb=&hbuf[0][0][0]; for (int i=tid;i<16*136;i+=512) hb[i]=0; }

  const int tt0 = dir? (TSTEPS-1):0;
  const long long d4 = dir? -(long long)GIDX_N : (long long)GIDX_N;
  const size_t gbase = ((size_t)dir*TSTEPS + (size_t)tt0)*GIDX_N
                     + (size_t)((btile*8+wave)*64+lane);
  const uint4* q4p = xp4 + gbase;
  const uint2* q2p = xp2 + gbase;
  uint4 q40 = q4p[0], q41 = q4p[d4];
  uint2 q20 = q2p[0], q21 = q2p[d4];
  const uint4* f4 = q4p + 2*d4;
  const uint2* f2 = q2p + 2*d4;

  float* op = out + 8192 + (size_t)tt0*(BATCH*2*HID)
            + (size_t)(b0 + lgrp*4)*(2*HID) + dir*HID + hcol;
  const long long odel = dir? -(long long)(BATCH*2*HID) : (long long)(BATCH*2*HID);

  float hm[4]={0,0,0,0};
  __syncthreads();

  for (int s=0;s<TSTEPS;++s){
    const int cur=s&1, nxt=cur^1;
    // depth-2 prefetch (wrap-safe inside xp4/xp2 allocations)
    uint4 q42 = *f4; f4 += d4;
    uint2 q22 = *f2; f2 += d4;

    f32x4 ar={0,0,0,0}, az={0,0,0,0}, an={0,0,0,0};
    #pragma unroll
    for (int kk=0;kk<4;++kk){
      bf16x8 a = *(const bf16x8*)&hbuf[cur][lrow][kk*32 + lgrp*8];
      ar = __builtin_amdgcn_mfma_f32_16x16x32_bf16(a, whh[0][kk], ar, 0,0,0);
      az = __builtin_amdgcn_mfma_f32_16x16x32_bf16(a, whh[1][kk], az, 0,0,0);
      an = __builtin_amdgcn_mfma_f32_16x16x32_bf16(a, whh[2][kk], an, 0,0,0);
    }

    float hv[4];
    {
      const float xr[4] = {bflo(q40.x),bfhi(q40.x),bflo(q40.y),bfhi(q40.y)};
      const float xz[4] = {bflo(q40.z),bfhi(q40.z),bflo(q40.w),bfhi(q40.w)};
      const float xn[4] = {bflo(q20.x),bfhi(q20.x),bflo(q20.y),bfhi(q20.y)};
      #pragma unroll
      for (int i=0;i<4;++i){
        const float r = __builtin_amdgcn_rcpf(1.f + __builtin_amdgcn_exp2f(-(ar[i]+xr[i])));
        const float z = __builtin_amdgcn_rcpf(1.f + __builtin_amdgcn_exp2f(-(az[i]+xz[i])));
        const float y  = fmaf(r, an[i]+bh2s, xn[i]);
        const float y2 = y + y;
        const float e  = __builtin_amdgcn_exp2f(fabsf(y2));
        const float t  = fmaf(-2.f, __builtin_amdgcn_rcpf(e+1.f), 1.f);
        const float n  = copysignf(t, y);
        hv[i] = fmaf(z, hm[i]-n, n);
        hm[i] = hv[i];
      }
    }
    const uint p01 = pk2(hv[0],hv[1]);
    const uint p23 = pk2(hv[2],hv[3]);
    hbuf[nxt][lgrp*4+0][hcol] = (ushort)p01;
    hbuf[nxt][lgrp*4+1][hcol] = (ushort)(p01>>16);
    hbuf[nxt][lgrp*4+2][hcol] = (ushort)p23;
    hbuf[nxt][lgrp*4+3][hcol] = (ushort)(p23>>16);
    op[0]   = hv[0];
    op[256] = hv[1];
    op[512] = hv[2];
    op[768] = hv[3];
    op += odel;
    q40=q41; q41=q42; q20=q21; q21=q22;
    asm volatile("s_waitcnt lgkmcnt(0)\n\ts_barrier" ::: "memory");
  }
}

// ============================================================================
// Fallback fused kernel (used only if ws_size is too small)
// ============================================================================
__global__ __launch_bounds__(512) void gru_fused(
    const float* __restrict__ y_aux,
    const float* __restrict__ W_ih_f, const float* __restrict__ W_hh_f,
    const float* __restrict__ b_ih_f, const float* __restrict__ b_hh_f,
    const float* __restrict__ W_ih_b, const float* __restrict__ W_hh_b,
    const float* __restrict__ b_ih_b, const float* __restrict__ b_hh_b,
    float* __restrict__ out)
{
  const int blk  = blockIdx.x;
  const int dir  = blk >> 4;
  const int b0   = (blk & 15) << 4;
  const int tid  = threadIdx.x;
  const int wave = tid >> 6;
  const int lane = tid & 63;
  const int lrow = lane & 15;
  const int lgrp = lane >> 4;

  const float* Wih = dir ? W_ih_b : W_ih_f;
  const float* Whh = dir ? W_hh_b : W_hh_f;
  const float* bih = dir ? b_ih_b : b_ih_f;
  const float* bhh = dir ? b_hh_b : b_hh_f;

  __shared__ __align__(16) ushort hbuf[2][16][136];
  __shared__ __align__(16) ushort xbuf[2][16][264];

  bf16x8 wih_f[3][8];
  bf16x8 whh_f[3][4];
  #pragma unroll
  for (int t3 = 0; t3 < 3; ++t3){
    const int g = t3*128 + wave*16 + lrow;
    #pragma unroll
    for (int kk = 0; kk < 8; ++kk) wih_f[t3][kk] = ld_w8(Wih + g*NIN + kk*32 + lgrp*8);
    #pragma unroll
    for (int kk = 0; kk < 4; ++kk) whh_f[t3][kk] = ld_w8(Whh + g*HID + kk*32 + lgrp*8);
  }
  float bihv[3], bhhv[3];
  #pragma unroll
  for (int t3 = 0; t3 < 3; ++t3){
    const int g = t3*128 + wave*16 + lrow;
    bihv[t3] = bih[g];
    bhhv[t3] = bhh[g];
  }

  for (int i = tid; i < 2*16*136; i += 512) ((ushort*)hbuf)[i] = 0;
  {
    const int row = tid >> 5, f8 = tid & 31;
    const int t0  = dir ? (TSTEPS-1) : 0;
    const float* p = y_aux + (size_t)(b0+row)*(TSTEPS*NIN) + (size_t)t0*NIN + f8*8;
    union{uint u[4]; bf16x8 v;} c;
    float4 a = *(const float4*)p; float4 b = *(const float4*)(p+4);
    c.u[0]=pk2(a.x,a.y); c.u[1]=pk2(a.z,a.w); c.u[2]=pk2(b.x,b.y); c.u[3]=pk2(b.z,b.w);
    *(bf16x8*)&xbuf[0][row][f8*8] = c.v;
  }
  __syncthreads();

  float hm[4] = {0.f, 0.f, 0.f, 0.f};
  const int hcol = wave*16 + lrow;
  float* outr = out + 8192;

  for (int s = 0; s < TSTEPS; ++s){
    const int tt  = dir ? (TSTEPS-1-s) : s;
    const int cur = s & 1, nxt = cur ^ 1;
    const int tn   = dir ? (tt-1) : (tt+1);
    const int prow = tid >> 5, pf8 = tid & 31;
    const bool more = (s < TSTEPS-1);
    float4 pa, pb;
    if (more){
      const float* p = y_aux + (size_t)(b0+prow)*(TSTEPS*NIN) + (size_t)tn*NIN + pf8*8;
      pa = *(const float4*)p;
      pb = *(const float4*)(p+4);
    }

    f32x4 a_rh = {0,0,0,0}, a_zh = {0,0,0,0}, a_nh = {0,0,0,0};
    f32x4 a_rx = {0,0,0,0}, a_zx = {0,0,0,0}, a_nx = {0,0,0,0};
    #pragma unroll
    for (int kk = 0; kk < 4; ++kk){
      bf16x8 a = *(const bf16x8*)&hbuf[cur][lrow][kk*32 + lgrp*8];
      a_rh = __builtin_amdgcn_mfma_f32_16x16x32_bf16(a, whh_f[0][kk], a_rh, 0,0,0);
      a_zh = __builtin_amdgcn_mfma_f32_16x16x32_bf16(a, whh_f[1][kk], a_zh, 0,0,0);
      a_nh = __builtin_amdgcn_mfma_f32_16x16x32_bf16(a, whh_f[2][kk], a_nh, 0,0,0);
    }
    #pragma unroll
    for (int kk = 0; kk < 8; ++kk){
      bf16x8 a = *(const bf16x8*)&xbuf[cur][lrow][kk*32 + lgrp*8];
      a_rx = __builtin_amdgcn_mfma_f32_16x16x32_bf16(a, wih_f[0][kk], a_rx, 0,0,0);
      a_zx = __builtin_amdgcn_mfma_f32_16x16x32_bf16(a, wih_f[1][kk], a_zx, 0,0,0);
      a_nx = __builtin_amdgcn_mfma_f32_16x16x32_bf16(a, wih_f[2][kk], a_nx, 0,0,0);
    }

    #pragma unroll
    for (int i = 0; i < 4; ++i){
      const float rp  = a_rh[i] + a_rx[i] + bihv[0] + bhhv[0];
      const float zp  = a_zh[i] + a_zx[i] + bihv[1] + bhhv[1];
      const float hnp = a_nh[i] + bhhv[2];
      const float xnp = a_nx[i] + bihv[2];
      const float r = sigmoid_fast(rp);
      const float z = sigmoid_fast(zp);
      const float n = tanh_fast(fmaf(r, hnp, xnp));
      const float hv = n + z*(hm[i] - n);
      hm[i] = hv;
      outr[(size_t)tt*(BATCH*2*HID) + (size_t)(b0 + lgrp*4 + i)*(2*HID)
           + dir*HID + hcol] = hv;
      hbuf[nxt][lgrp*4 + i][hcol] = f2bf(hv);
    }

    if (more){
      union{uint u[4]; bf16x8 v;} c;
      c.u[0]=pk2(pa.x,pa.y); c.u[1]=pk2(pa.z,pa.w); c.u[2]=pk2(pb.x,pb.y); c.u[3]=pk2(pb.z,pb.w);
      *(bf16x8*)&xbuf[nxt][prow][pf8*8] = c.v;
    }
    __syncthreads();
  }
}

// mu_0 / log_var_0 heads: temp = [zeros(B,L), hn0], so only W[:, L:] matters.
__global__ void heads(const float* __restrict__ out_rnn,
    const float* __restrict__ W_mu, const float* __restrict__ b_mu,
    const float* __restrict__ W_lv, const float* __restrict__ b_lv,
    float* __restrict__ out)
{
  const int oid   = blockIdx.x*256 + threadIdx.x;
  const int which = oid >> 12;
  const int r     = oid & 4095;
  const int b = r >> 4, j = r & 15;
  const float* W    = which ? W_lv : W_mu;
  const float* bias = which ? b_lv : b_mu;
  const float* h = out_rnn + b*256;
  const float* w = W + j*272 + 16;
  float acc = bias[j];
  for (int c = 0; c < 256; c += 4){
    acc += h[c]*w[c] + h[c+1]*w[c+1] + h[c+2]*w[c+2] + h[c+3]*w[c+3];
  }
  out[(which << 12) + r] = acc;
}

extern "C" void kernel_launch(void* const* d_in, const int* in_sizes, int n_in,
                              void* d_out, int out_size, void* d_ws, size_t ws_size,
                              hipStream_t stream)
{
  const float* y    = (const float*)d_in[0];
  const float* Wihf = (const float*)d_in[1];
  const float* Whhf = (const float*)d_in[2];
  const float* bihf = (const float*)d_in[3];
  const float* bhhf = (const float*)d_in[4];
  const float* Wihb = (const float*)d_in[5];
  const float* Whhb = (const float*)d_in[6];
  const float* bihb = (const float*)d_in[7];
  const float* bhhb = (const float*)d_in[8];
  const float* Wmu  = (const float*)d_in[9];
  const float* bmu  = (const float*)d_in[10];
  const float* Wlv  = (const float*)d_in[11];
  const float* blv  = (const float*)d_in[12];
  float* out = (float*)d_out;

  if (ws_size >= (size_t)XP_NEED){
    uint4* xp4 = (uint4*)d_ws;
    uint2* xp2 = (uint2*)((char*)d_ws + XP2_OFF_BYTES);
    xp_gemm<<<dim3(2*16*(TSTEPS/TC)), dim3(512), 0, stream>>>(
        y, Wihf, bihf, bhhf, Wihb, bihb, bhhb, xp4, xp2);
    gru_rec<<<dim3(32), dim3(512), 0, stream>>>(
        xp4, xp2, Whhf, bhhf, Whhb, bhhb, out);
  } else {
    gru_fused<<<dim3(32), dim3(512), 0, stream>>>(
        y, Wihf, Whhf, bihf, bhhf, Wihb, Whhb, bihb, bhhb, out);
  }
  heads<<<dim3(32), dim3(256), 0, stream>>>(out + 8192, Wmu, bmu, Wlv, blv, out);
}

// Round 14
// 908.444 us; speedup vs baseline: 1.3814x; 1.0299x over previous
//
#include <hip/hip_runtime.h>
#include <hip/hip_bf16.h>

typedef short bf16x8 __attribute__((ext_vector_type(8)));
typedef float f32x4  __attribute__((ext_vector_type(4)));

#define TSTEPS 1000
#define BATCH  256
#define NIN    256
#define HID    128
#define TC     50                      // MUST be even (pair-unrolled loop); 640 blocks = xp_gemm optimum
#define LOG2E  1.44269504088896f

// SoA xp: xp4 = uint4 {r01,r23,z01,z23}, xp2 = uint2 {n01,n23}; ALL preacts
// prescaled by log2e; r,z have bih+bhh folded, n has bih folded (bhh_n is
// added in gru_rec's gate code). index = (dir*TSTEPS+t)*8192 + gidx,
// gidx = (btile*8+wave)*64+lane.
#define GIDX_N 8192
#define XP4_ELEMS (2ull*TSTEPS*GIDX_N)
#define XP2_OFF_BYTES (XP4_ELEMS*16ull)           // 262,144,000
#define XP_NEED (XP4_ELEMS*16ull + 2ull*TSTEPS*GIDX_N*8ull)   // 393,216,000

__device__ __forceinline__ ushort f2bf(float f){
  union { float f; unsigned u; } v; v.f = f;
  unsigned r = v.u + 0x7fffu + ((v.u >> 16) & 1u);
  return (ushort)(r >> 16);
}
__device__ __forceinline__ uint pk2(float lo, float hi){
  __hip_bfloat162 h = __float22bfloat162_rn(make_float2(lo, hi));
  union { __hip_bfloat162 h; uint u; } c; c.h = h; return c.u;
}
__device__ __forceinline__ float bflo(uint w){ union{uint u;float f;}c; c.u = w<<16; return c.f; }
__device__ __forceinline__ float bfhi(uint w){ union{uint u;float f;}c; c.u = w & 0xffff0000u; return c.f; }

__device__ __forceinline__ float sigmoid_fast(float x){
  return __builtin_amdgcn_rcpf(1.f + __expf(-x));
}
__device__ __forceinline__ float tanh_fast(float a){
  const float e = __expf(2.f*fabsf(a));
  const float t = fmaf(-2.f, __builtin_amdgcn_rcpf(e + 1.f), 1.f);
  return copysignf(t, a);
}
__device__ __forceinline__ bf16x8 ld_w8(const float* p){
  union { uint u[4]; bf16x8 v; } c;
  c.u[0]=pk2(p[0],p[1]); c.u[1]=pk2(p[2],p[3]);
  c.u[2]=pk2(p[4],p[5]); c.u[3]=pk2(p[6],p[7]);
  return c.v;
}
__device__ __forceinline__ bf16x8 ld_w8s(const float* p, float s){
  union { uint u[4]; bf16x8 v; } c;
  c.u[0]=pk2(p[0]*s,p[1]*s); c.u[1]=pk2(p[2]*s,p[3]*s);
  c.u[2]=pk2(p[4]*s,p[5]*s); c.u[3]=pk2(p[6]*s,p[7]*s);
  return c.v;
}

// ============================================================================
// Input-projection GEMM (verified-best configuration: staged, TC=50 ->
// 640 blocks, ~205us measured). Weights prescaled by log2e; biases folded
// via loop-invariant MFMA C-init; depth-2 register prefetch, clamped.
// ============================================================================
__global__ __launch_bounds__(512) void xp_gemm(
    const float* __restrict__ y_aux,
    const float* __restrict__ Wf, const float* __restrict__ bihf, const float* __restrict__ bhhf,
    const float* __restrict__ Wb, const float* __restrict__ bihb, const float* __restrict__ bhhb,
    uint4* __restrict__ xp4, uint2* __restrict__ xp2)
{
  const int nch = TSTEPS/TC;               // 20
  const int blk = blockIdx.x;
  const int dir = blk / (16*nch);
  const int rem = blk % (16*nch);
  const int btile = rem / nch;
  const int tch = rem % nch;
  const int b0 = btile*16;
  const int tid=threadIdx.x, wave=tid>>6, lane=tid&63, lrow=lane&15, lgrp=lane>>4;
  const float* Wih = dir? Wb : Wf;
  const float* bih = dir? bihb : bihf;
  const float* bhh = dir? bhhb : bhhf;

  __shared__ __align__(16) ushort xsh[2][16][264];

  bf16x8 wf[3][8];
  f32x4 cinit[3];
  #pragma unroll
  for (int t3=0;t3<3;++t3){
    const int g = t3*128 + wave*16 + lrow;
    #pragma unroll
    for (int kk=0;kk<8;++kk)
      wf[t3][kk] = ld_w8s(Wih + g*NIN + kk*32 + lgrp*8, LOG2E);
    const float bv = LOG2E * (bih[g] + (t3<2 ? bhh[g] : 0.f));
    cinit[t3][0]=bv; cinit[t3][1]=bv; cinit[t3][2]=bv; cinit[t3][3]=bv;
  }

  const int row = tid>>5, f8 = tid&31;
  const float* xsrc = y_aux + (size_t)(b0+row)*(TSTEPS*NIN) + (size_t)(tch*TC)*NIN + f8*8;
  {
    float4 a = *(const float4*)xsrc;
    float4 b = *(const float4*)(xsrc+4);
    union{uint u[4]; bf16x8 v;} c;
    c.u[0]=pk2(a.x,a.y); c.u[1]=pk2(a.z,a.w); c.u[2]=pk2(b.x,b.y); c.u[3]=pk2(b.z,b.w);
    *(bf16x8*)&xsh[0][row][f8*8] = c.v;
  }
  // depth-2 prefetch: t=1 and t=2 (TC >= 3)
  float4 Aa = *(const float4*)(xsrc + 1*NIN), Ab = *(const float4*)(xsrc + 1*NIN + 4);
  float4 Ba = *(const float4*)(xsrc + 2*NIN), Bb = *(const float4*)(xsrc + 2*NIN + 4);
  __syncthreads();

  size_t sidx = ((size_t)dir*TSTEPS + (size_t)(tch*TC))*GIDX_N
              + (size_t)((btile*8 + wave)*64 + lane);

  for (int k=0;k<TC;k+=2){
    // ----- step k (reads xsh[0], writes Aa/Ab -> xsh[1]) -----
    {
      f32x4 a0=cinit[0], a1=cinit[1], a2=cinit[2];
      #pragma unroll
      for (int kk=0;kk<8;++kk){
        bf16x8 a = *(const bf16x8*)&xsh[0][lrow][kk*32 + lgrp*8];
        a0 = __builtin_amdgcn_mfma_f32_16x16x32_bf16(a, wf[0][kk], a0, 0,0,0);
        a1 = __builtin_amdgcn_mfma_f32_16x16x32_bf16(a, wf[1][kk], a1, 0,0,0);
        a2 = __builtin_amdgcn_mfma_f32_16x16x32_bf16(a, wf[2][kk], a2, 0,0,0);
      }
      uint4 o4; o4.x=pk2(a0[0],a0[1]); o4.y=pk2(a0[2],a0[3]);
                o4.z=pk2(a1[0],a1[1]); o4.w=pk2(a1[2],a1[3]);
      uint2 o2; o2.x=pk2(a2[0],a2[1]); o2.y=pk2(a2[2],a2[3]);
      xp4[sidx]=o4; xp2[sidx]=o2; sidx += GIDX_N;
      union{uint u[4]; bf16x8 v;} c;
      c.u[0]=pk2(Aa.x,Aa.y); c.u[1]=pk2(Aa.z,Aa.w); c.u[2]=pk2(Ab.x,Ab.y); c.u[3]=pk2(Ab.z,Ab.w);
      *(bf16x8*)&xsh[1][row][f8*8] = c.v;
      const int t3 = (k+3 <= TC-1) ? (k+3) : (TC-1);     // uniform, clamped
      Aa = *(const float4*)(xsrc + (size_t)t3*NIN);
      Ab = *(const float4*)(xsrc + (size_t)t3*NIN + 4);
      asm volatile("s_waitcnt lgkmcnt(0)\n\ts_barrier" ::: "memory");
    }
    // ----- step k+1 (reads xsh[1], writes Ba/Bb -> xsh[0]) -----
    {
      f32x4 a0=cinit[0], a1=cinit[1], a2=cinit[2];
      #pragma unroll
      for (int kk=0;kk<8;++kk){
        bf16x8 a = *(const bf16x8*)&xsh[1][lrow][kk*32 + lgrp*8];
        a0 = __builtin_amdgcn_mfma_f32_16x16x32_bf16(a, wf[0][kk], a0, 0,0,0);
        a1 = __builtin_amdgcn_mfma_f32_16x16x32_bf16(a, wf[1][kk], a1, 0,0,0);
        a2 = __builtin_amdgcn_mfma_f32_16x16x32_bf16(a, wf[2][kk], a2, 0,0,0);
      }
      uint4 o4; o4.x=pk2(a0[0],a0[1]); o4.y=pk2(a0[2],a0[3]);
                o4.z=pk2(a1[0],a1[1]); o4.w=pk2(a1[2],a1[3]);
      uint2 o2; o2.x=pk2(a2[0],a2[1]); o2.y=pk2(a2[2],a2[3]);
      xp4[sidx]=o4; xp2[sidx]=o2; sidx += GIDX_N;
      union{uint u[4]; bf16x8 v;} c;
      c.u[0]=pk2(Ba.x,Ba.y); c.u[1]=pk2(Ba.z,Ba.w); c.u[2]=pk2(Bb.x,Bb.y); c.u[3]=pk2(Bb.z,Bb.w);
      *(bf16x8*)&xsh[0][row][f8*8] = c.v;
      const int t4 = (k+4 <= TC-1) ? (k+4) : (TC-1);
      Ba = *(const float4*)(xsrc + (size_t)t4*NIN);
      Bb = *(const float4*)(xsrc + (size_t)t4*NIN + 4);
      asm volatile("s_waitcnt lgkmcnt(0)\n\ts_barrier" ::: "memory");
    }
  }
}

// ============================================================================
// Serial recurrence — R3 VERBATIM (measured 690-704us across 5 benches).
// 32 blocks (dir x btile), 8 waves; wave w owns gate tiles {w, 8+w, 16+w}
// = (r,z,n) for h columns [16w,16w+16). Zero-init accumulators, xp added
// post-MFMA, depth-2 prefetch.
// ============================================================================
__global__ __launch_bounds__(512) void gru_rec(
    const uint4* __restrict__ xp4, const uint2* __restrict__ xp2,
    const float* __restrict__ Whhf, const float* __restrict__ bhhf,
    const float* __restrict__ Whhb, const float* __restrict__ bhhb,
    float* __restrict__ out)
{
  const int blk=blockIdx.x, dir=blk>>4, btile=blk&15, b0=btile<<4;
  const int tid=threadIdx.x, wave=tid>>6, lane=tid&63, lrow=lane&15, lgrp=lane>>4;
  const float* Whh = dir? Whhb : Whhf;
  const float* bhh = dir? bhhb : bhhf;

  __shared__ __align__(16) ushort hbuf[2][16][136];

  bf16x8 whh[3][4];
  #pragma unroll
  for (int t3=0;t3<3;++t3){
    const int g = t3*128 + wave*16 + lrow;
    #pragma unroll
    for (int kk=0;kk<4;++kk)
      whh[t3][kk] = ld_w8s(Whh + g*HID + kk*32 + lgrp*8, LOG2E);
  }
  const int hcol = wave*16 + lrow;
  const float bh2s = LOG2E * bhh[256 + hcol];

  { ushort* hb=&hbuf[0][0][0]; for (int i=tid;i<16*136;i+=512) hb[i]=0; }

  const int tt0 = dir? (TSTEPS-1):0;
  const long long d4 = dir? -(long long)GIDX_N : (long long)GIDX_N;
  const size_t gbase = ((size_t)dir*TSTEPS + (size_t)tt0)*GIDX_N
                     + (size_t)((btile*8+wave)*64+lane);
  const uint4* q4p = xp4 + gbase;
  const uint2* q2p = xp2 + gbase;
  uint4 q40 = q4p[0], q41 = q4p[d4];
  uint2 q20 = q2p[0], q21 = q2p[d4];
  const uint4* f4 = q4p + 2*d4;
  const uint2* f2 = q2p + 2*d4;

  float* op = out + 8192 + (size_t)tt0*(BATCH*2*HID)
            + (size_t)(b0 + lgrp*4)*(2*HID) + dir*HID + hcol;
  const long long odel = dir? -(long long)(BATCH*2*HID) : (long long)(BATCH*2*HID);

  float hm[4]={0,0,0,0};
  __syncthreads();

  for (int s=0;s<TSTEPS;++s){
    const int cur=s&1, nxt=cur^1;
    // depth-2 prefetch (wrap-safe inside xp4/xp2 allocations)
    uint4 q42 = *f4; f4 += d4;
    uint2 q22 = *f2; f2 += d4;

    f32x4 ar={0,0,0,0}, az={0,0,0,0}, an={0,0,0,0};
    #pragma unroll
    for (int kk=0;kk<4;++kk){
      bf16x8 a = *(const bf16x8*)&hbuf[cur][lrow][kk*32 + lgrp*8];
      ar = __builtin_amdgcn_mfma_f32_16x16x32_bf16(a, whh[0][kk], ar, 0,0,0);
      az = __builtin_amdgcn_mfma_f32_16x16x32_bf16(a, whh[1][kk], az, 0,0,0);
      an = __builtin_amdgcn_mfma_f32_16x16x32_bf16(a, whh[2][kk], an, 0,0,0);
    }

    float hv[4];
    {
      const float xr[4] = {bflo(q40.x),bfhi(q40.x),bflo(q40.y),bfhi(q40.y)};
      const float xz[4] = {bflo(q40.z),bfhi(q40.z),bflo(q40.w),bfhi(q40.w)};
      const float xn[4] = {bflo(q20.x),bfhi(q20.x),bflo(q20.y),bfhi(q20.y)};
      #pragma unroll
      for (int i=0;i<4;++i){
        const float r = __builtin_amdgcn_rcpf(1.f + __builtin_amdgcn_exp2f(-(ar[i]+xr[i])));
        const float z = __builtin_amdgcn_rcpf(1.f + __builtin_amdgcn_exp2f(-(az[i]+xz[i])));
        const float y  = fmaf(r, an[i]+bh2s, xn[i]);
        const float y2 = y + y;
        const float e  = __builtin_amdgcn_exp2f(fabsf(y2));
        const float t  = fmaf(-2.f, __builtin_amdgcn_rcpf(e+1.f), 1.f);
        const float n  = copysignf(t, y);
        hv[i] = fmaf(z, hm[i]-n, n);
        hm[i] = hv[i];
      }
    }
    const uint p01 = pk2(hv[0],hv[1]);
    const uint p23 = pk2(hv[2],hv[3]);
    hbuf[nxt][lgrp*4+0][hcol] = (ushort)p01;
    hbuf[nxt][lgrp*4+1][hcol] = (ushort)(p01>>16);
    hbuf[nxt][lgrp*4+2][hcol] = (ushort)p23;
    hbuf[nxt][lgrp*4+3][hcol] = (ushort)(p23>>16);
    op[0]   = hv[0];
    op[256] = hv[1];
    op[512] = hv[2];
    op[768] = hv[3];
    op += odel;
    q40=q41; q41=q42; q20=q21; q21=q22;
    asm volatile("s_waitcnt lgkmcnt(0)\n\ts_barrier" ::: "memory");
  }
}

// ============================================================================
// Fallback fused kernel (used only if ws_size is too small)
// ============================================================================
__global__ __launch_bounds__(512) void gru_fused(
    const float* __restrict__ y_aux,
    const float* __restrict__ W_ih_f, const float* __restrict__ W_hh_f,
    const float* __restrict__ b_ih_f, const float* __restrict__ b_hh_f,
    const float* __restrict__ W_ih_b, const float* __restrict__ W_hh_b,
    const float* __restrict__ b_ih_b, const float* __restrict__ b_hh_b,
    float* __restrict__ out)
{
  const int blk  = blockIdx.x;
  const int dir  = blk >> 4;
  const int b0   = (blk & 15) << 4;
  const int tid  = threadIdx.x;
  const int wave = tid >> 6;
  const int lane = tid & 63;
  const int lrow = lane & 15;
  const int lgrp = lane >> 4;

  const float* Wih = dir ? W_ih_b : W_ih_f;
  const float* Whh = dir ? W_hh_b : W_hh_f;
  const float* bih = dir ? b_ih_b : b_ih_f;
  const float* bhh = dir ? b_hh_b : b_hh_f;

  __shared__ __align__(16) ushort hbuf[2][16][136];
  __shared__ __align__(16) ushort xbuf[2][16][264];

  bf16x8 wih_f[3][8];
  bf16x8 whh_f[3][4];
  #pragma unroll
  for (int t3 = 0; t3 < 3; ++t3){
    const int g = t3*128 + wave*16 + lrow;
    #pragma unroll
    for (int kk = 0; kk < 8; ++kk) wih_f[t3][kk] = ld_w8(Wih + g*NIN + kk*32 + lgrp*8);
    #pragma unroll
    for (int kk = 0; kk < 4; ++kk) whh_f[t3][kk] = ld_w8(Whh + g*HID + kk*32 + lgrp*8);
  }
  float bihv[3], bhhv[3];
  #pragma unroll
  for (int t3 = 0; t3 < 3; ++t3){
    const int g = t3*128 + wave*16 + lrow;
    bihv[t3] = bih[g];
    bhhv[t3] = bhh[g];
  }

  for (int i = tid; i < 2*16*136; i += 512) ((ushort*)hbuf)[i] = 0;
  {
    const int row = tid >> 5, f8 = tid & 31;
    const int t0  = dir ? (TSTEPS-1) : 0;
    const float* p = y_aux + (size_t)(b0+row)*(TSTEPS*NIN) + (size_t)t0*NIN + f8*8;
    union{uint u[4]; bf16x8 v;} c;
    float4 a = *(const float4*)p; float4 b = *(const float4*)(p+4);
    c.u[0]=pk2(a.x,a.y); c.u[1]=pk2(a.z,a.w); c.u[2]=pk2(b.x,b.y); c.u[3]=pk2(b.z,b.w);
    *(bf16x8*)&xbuf[0][row][f8*8] = c.v;
  }
  __syncthreads();

  float hm[4] = {0.f, 0.f, 0.f, 0.f};
  const int hcol = wave*16 + lrow;
  float* outr = out + 8192;

  for (int s = 0; s < TSTEPS; ++s){
    const int tt  = dir ? (TSTEPS-1-s) : s;
    const int cur = s & 1, nxt = cur ^ 1;
    const int tn   = dir ? (tt-1) : (tt+1);
    const int prow = tid >> 5, pf8 = tid & 31;
    const bool more = (s < TSTEPS-1);
    float4 pa, pb;
    if (more){
      const float* p = y_aux + (size_t)(b0+prow)*(TSTEPS*NIN) + (size_t)tn*NIN + pf8*8;
      pa = *(const float4*)p;
      pb = *(const float4*)(p+4);
    }

    f32x4 a_rh = {0,0,0,0}, a_zh = {0,0,0,0}, a_nh = {0,0,0,0};
    f32x4 a_rx = {0,0,0,0}, a_zx = {0,0,0,0}, a_nx = {0,0,0,0};
    #pragma unroll
    for (int kk = 0; kk < 4; ++kk){
      bf16x8 a = *(const bf16x8*)&hbuf[cur][lrow][kk*32 + lgrp*8];
      a_rh = __builtin_amdgcn_mfma_f32_16x16x32_bf16(a, whh_f[0][kk], a_rh, 0,0,0);
      a_zh = __builtin_amdgcn_mfma_f32_16x16x32_bf16(a, whh_f[1][kk], a_zh, 0,0,0);
      a_nh = __builtin_amdgcn_mfma_f32_16x16x32_bf16(a, whh_f[2][kk], a_nh, 0,0,0);
    }
    #pragma unroll
    for (int kk = 0; kk < 8; ++kk){
      bf16x8 a = *(const bf16x8*)&xbuf[cur][lrow][kk*32 + lgrp*8];
      a_rx = __builtin_amdgcn_mfma_f32_16x16x32_bf16(a, wih_f[0][kk], a_rx, 0,0,0);
      a_zx = __builtin_amdgcn_mfma_f32_16x16x32_bf16(a, wih_f[1][kk], a_zx, 0,0,0);
      a_nx = __builtin_amdgcn_mfma_f32_16x16x32_bf16(a, wih_f[2][kk], a_nx, 0,0,0);
    }

    #pragma unroll
    for (int i = 0; i < 4; ++i){
      const float rp  = a_rh[i] + a_rx[i] + bihv[0] + bhhv[0];
      const float zp  = a_zh[i] + a_zx[i] + bihv[1] + bhhv[1];
      const float hnp = a_nh[i] + bhhv[2];
      const float xnp = a_nx[i] + bihv[2];
      const float r = sigmoid_fast(rp);
      const float z = sigmoid_fast(zp);
      const float n = tanh_fast(fmaf(r, hnp, xnp));
      const float hv = n + z*(hm[i] - n);
      hm[i] = hv;
      outr[(size_t)tt*(BATCH*2*HID) + (size_t)(b0 + lgrp*4 + i)*(2*HID)
           + dir*HID + hcol] = hv;
      hbuf[nxt][lgrp*4 + i][hcol] = f2bf(hv);
    }

    if (more){
      union{uint u[4]; bf16x8 v;} c;
      c.u[0]=pk2(pa.x,pa.y); c.u[1]=pk2(pa.z,pa.w); c.u[2]=pk2(pb.x,pb.y); c.u[3]=pk2(pb.z,pb.w);
      *(bf16x8*)&xbuf[nxt][prow][pf8*8] = c.v;
    }
    __syncthreads();
  }
}

// mu_0 / log_var_0 heads: temp = [zeros(B,L), hn0], so only W[:, L:] matters.
__global__ void heads(const float* __restrict__ out_rnn,
    const float* __restrict__ W_mu, const float* __restrict__ b_mu,
    const float* __restrict__ W_lv, const float* __restrict__ b_lv,
    float* __restrict__ out)
{
  const int oid   = blockIdx.x*256 + threadIdx.x;
  const int which = oid >> 12;
  const int r     = oid & 4095;
  const int b = r >> 4, j = r & 15;
  const float* W    = which ? W_lv : W_mu;
  const float* bias = which ? b_lv : b_mu;
  const float* h = out_rnn + b*256;
  const float* w = W + j*272 + 16;
  float acc = bias[j];
  for (int c = 0; c < 256; c += 4){
    acc += h[c]*w[c] + h[c+1]*w[c+1] + h[c+2]*w[c+2] + h[c+3]*w[c+3];
  }
  out[(which << 12) + r] = acc;
}

extern "C" void kernel_launch(void* const* d_in, const int* in_sizes, int n_in,
                              void* d_out, int out_size, void* d_ws, size_t ws_size,
                              hipStream_t stream)
{
  const float* y    = (const float*)d_in[0];
  const float* Wihf = (const float*)d_in[1];
  const float* Whhf = (const float*)d_in[2];
  const float* bihf = (const float*)d_in[3];
  const float* bhhf = (const float*)d_in[4];
  const float* Wihb = (const float*)d_in[5];
  const float* Whhb = (const float*)d_in[6];
  const float* bihb = (const float*)d_in[7];
  const float* bhhb = (const float*)d_in[8];
  const float* Wmu  = (const float*)d_in[9];
  const float* bmu  = (const float*)d_in[10];
  const float* Wlv  = (const float*)d_in[11];
  const float* blv  = (const float*)d_in[12];
  float* out = (float*)d_out;

  if (ws_size >= (size_t)XP_NEED){
    uint4* xp4 = (uint4*)d_ws;
    uint2* xp2 = (uint2*)((char*)d_ws + XP2_OFF_BYTES);
    xp_gemm<<<dim3(2*16*(TSTEPS/TC)), dim3(512), 0, stream>>>(
        y, Wihf, bihf, bhhf, Wihb, bihb, bhhb, xp4, xp2);
    gru_rec<<<dim3(32), dim3(512), 0, stream>>>(
        xp4, xp2, Whhf, bhhf, Whhb, bhhb, out);
  } else {
    gru_fused<<<dim3(32), dim3(512), 0, stream>>>(
        y, Wihf, Whhf, bihf, bhhf, Wihb, Whhb, bihb, bhhb, out);
  }
  heads<<<dim3(32), dim3(256), 0, stream>>>(out + 8192, Wmu, bmu, Wlv, blv, out);
}